// Round 12
// baseline (321.111 us; speedup 1.0000x reference)
//
#include <hip/hip_runtime.h>
#include <math.h>

#define BB 2
#define HH 16
#define QQ 2048
#define SS 4096
#define DD 64
#define NRH 16    // half of N_ROTATE=32
#define NQT 32    // q-tiles of 64 per bh

typedef unsigned short u16;
typedef unsigned int   u32;
typedef short bhalf8 __attribute__((ext_vector_type(8)));  // 8 bf16 bit patterns
typedef float f32x4  __attribute__((ext_vector_type(4)));

typedef __attribute__((address_space(1))) const u32 gu32;
typedef __attribute__((address_space(3))) u32 lu32;

#if __has_builtin(__builtin_amdgcn_exp2f)
#define EXP2(x) __builtin_amdgcn_exp2f(x)
#else
#define EXP2(x) exp2f(x)
#endif

union Frag16 { uint4 u; bhalf8 v; u16 s[8]; uint2 d[2]; };

__device__ __forceinline__ u16 f2bf(float f) {  // RNE f32->bf16
  union { float f; u32 u; } c; c.f = f;
  return (u16)((c.u + 0x7FFFu + ((c.u >> 16) & 1u)) >> 16);
}

// packed RNE f32x2 -> bf16x2 (lo = first src)
__device__ __forceinline__ u32 cvt_pk_bf16(float lo, float hi) {
  u32 r;
  asm("v_cvt_pk_bf16_f32 %0, %1, %2" : "=v"(r) : "v"(lo), "v"(hi));
  return r;
}

__device__ __forceinline__ bhalf8 ldfrag(const u16* p) {
  Frag16 f; f.u = *reinterpret_cast<const uint4*>(p); return f.v;
}

__device__ __forceinline__ void rope32(float* x, int pos) {
  const float step = 0.8304820237218405f;  // log2(10000)/16
  const float fp = (float)pos;
#pragma unroll
  for (int i = 0; i < NRH; ++i) {
    float ang = fp * exp2f(-step * (float)i);
    float sv, cv;
    __sincosf(ang, &sv, &cv);
    float a = x[i], b = x[i + NRH];
    x[i]       = a * cv - b * sv;
    x[i + NRH] = b * cv + a * sv;
  }
}

// ---------------------------------------------------------------------------
// idx[b][0..2047] = ascending indices of true entries of skip_mask[b].
// ---------------------------------------------------------------------------
__device__ __forceinline__ void prep_idx_body(const unsigned char* __restrict__ sm,
                                              int* __restrict__ idx, int b,
                                              int* wsum, int* modes) {
  const int tid = threadIdx.x;  // 256

  int c = 0;
  for (int i = 0; i < 32; ++i) c += (sm[tid * 32 + i] != 0) ? 1 : 0;
#pragma unroll
  for (int off = 32; off; off >>= 1) c += __shfl_down(c, off);
  if ((tid & 63) == 0) wsum[tid >> 6] = c;
  __syncthreads();
  if (tid == 0) *modes = (wsum[0] + wsum[1] + wsum[2] + wsum[3] > 3000) ? 1 : 0;
  __syncthreads();
  const bool byteMode = (*modes != 0);
  const u32* sm32 = (const u32*)sm;

  const int base = b * SS + tid * 16;
  u32 flags = 0;
  for (int i = 0; i < 16; ++i) {
    bool f = byteMode ? (sm[base + i] != 0) : (sm32[base + i] != 0);
    flags |= ((u32)(f ? 1 : 0)) << i;
  }
  int cnt = __popc(flags);
  int vv = cnt;
#pragma unroll
  for (int off = 1; off < 64; off <<= 1) {
    int t = __shfl_up(vv, off);
    if ((tid & 63) >= off) vv += t;
  }
  __syncthreads();
  if ((tid & 63) == 63) wsum[tid >> 6] = vv;
  __syncthreads();
  int add = 0;
  for (int w2 = 0; w2 < (tid >> 6); ++w2) add += wsum[w2];
  int p = vv - cnt + add;
  for (int i = 0; i < 16; ++i) {
    if (flags & (1u << i)) {
      if (p < QQ) idx[b * QQ + p] = tid * 16 + i;
      ++p;
    }
  }
}

__global__ void prep_idx_kernel(const unsigned char* __restrict__ sm,
                                int* __restrict__ idx) {
  __shared__ int wsum[4];
  __shared__ int modes;
  prep_idx_body(sm, idx, (int)blockIdx.x, wsum, &modes);
}

// ---------------------------------------------------------------------------
// FUSED prep:
//   blocks [0,512):      k -> RoPE(pos=j) -> bf16 kbf[bh][j][d]
//   blocks [512,2560):   v -> bf16 FRAGMENT-ORDER layout vfrag[bh][tile][j][lane]
//                        (same bytes as round-11's verified layout; threads
//                        remapped so each wave writes 1KB contiguous):
//                        for (j,lane): d=(j>>1)*16+(lane&15), ch=(j&1)*4+(lane>>4),
//                        o[i]=V^T_kappa[d][ch*8+i], kappa(p)=(p&32)|((p&4)<<2)|
//                        ((p>>1)&12)|(p&3); dst = tile_base + j*1024 + lane*16.
//   blocks [2560,2562):  skip_mask -> idx (batch = blockIdx - 2560)
// ---------------------------------------------------------------------------
__global__ __launch_bounds__(256) void prep_fused_kernel(
    const float* __restrict__ k, const float* __restrict__ v,
    const unsigned char* __restrict__ skip,
    u16* __restrict__ kbf, u16* __restrict__ vfrag, int* __restrict__ idx) {
  __shared__ u16 tile[64][72];
  __shared__ int wsum[4];
  __shared__ int modes;
  if (blockIdx.x >= 2560) {
    prep_idx_body(skip, idx, (int)blockIdx.x - 2560, wsum, &modes);
  } else if (blockIdx.x < 512) {
    int r = blockIdx.x * 256 + threadIdx.x;  // 0..131071
    int pos = r & (SS - 1);
    float x[64];
    const float4* src = (const float4*)(k + (size_t)r * DD);
#pragma unroll
    for (int i = 0; i < 16; ++i) {
      float4 t = src[i];
      x[4 * i] = t.x; x[4 * i + 1] = t.y; x[4 * i + 2] = t.z; x[4 * i + 3] = t.w;
    }
    rope32(x, pos);
    u16 tmp[64];
#pragma unroll
    for (int i = 0; i < 64; ++i) tmp[i] = f2bf(x[i]);
    uint4* dst = (uint4*)(kbf + (size_t)r * DD);
#pragma unroll
    for (int i = 0; i < 8; ++i) dst[i] = ((uint4*)tmp)[i];
  } else {
    int blk = (int)blockIdx.x - 512;
    int bh = blk >> 6;
    int jt = blk & 63;
    int t = threadIdx.x;
    int jl = t >> 2;
    int dc = (t & 3) * 16;
    const float4* src = (const float4*)(v + ((size_t)(bh * SS + jt * 64 + jl)) * DD + dc);
#pragma unroll
    for (int i = 0; i < 4; ++i) {
      float4 f = src[i];
      tile[jl][dc + 4 * i]     = f2bf(f.x);
      tile[jl][dc + 4 * i + 1] = f2bf(f.y);
      tile[jl][dc + 4 * i + 2] = f2bf(f.z);
      tile[jl][dc + 4 * i + 3] = f2bf(f.w);
    }
    __syncthreads();
    const int lane = t & 63;
    const int jj = t >> 6;    // 0..3; thread covers j = jj and jj+4
    char* tb = (char*)vfrag + (size_t)bh * (SS * DD * 2) + (size_t)jt * 8192;
#pragma unroll
    for (int h = 0; h < 2; ++h) {
      int j = jj + h * 4;
      int d = ((j >> 1) << 4) + (lane & 15);
      int ch = ((j & 1) << 2) + (lane >> 4);
      u16 o[8];
#pragma unroll
      for (int i = 0; i < 8; ++i) {
        int p = ch * 8 + i;
        int kp = (p & 32) | ((p & 4) << 2) | ((p >> 1) & 12) | (p & 3);
        o[i] = tile[kp][d];
      }
      *(uint4*)(tb + j * 1024 + lane * 16) = *((uint4*)o);
    }
  }
}

// ---------------------------------------------------------------------------
// Staging: one 64-key K tile into LDS via global_load_lds (16B/lane), XOR
// swizzle applied on the GLOBAL address side: LDS[row][c] holds global chunk
// c^(row&7). V is NOT staged — read from global in fragment order
// (1KB-coalesced per instruction, L2/L1-resident).
// ---------------------------------------------------------------------------
__device__ __forceinline__ void stage_k(const char* kb_bh, u16* Kb, int t0,
                                        int w, int srow, int schk) {
#pragma unroll
  for (int p2 = 0; p2 < 2; ++p2) {
    const int rr = w * 16 + p2 * 8 + srow;
    const char* g = kb_bh + (size_t)(t0 + rr) * 128 + ((schk ^ (rr & 7)) * 16);
    lu32* l = (lu32*)((char*)Kb + (w * 16 + p2 * 8) * 128);
    __builtin_amdgcn_global_load_lds((gu32*)g, l, 16, 0, 0);
  }
}

// ---------------------------------------------------------------------------
// PV flush: the 8 PV MFMAs for a PREVIOUS tile — pure register inputs
// (pending V-frags + P^T packs), no memory dependencies.
// ---------------------------------------------------------------------------
__device__ __forceinline__ void pv_flush(
    bhalf8 px0, bhalf8 py0, bhalf8 px1, bhalf8 py1,
    bhalf8 px2, bhalf8 py2, bhalf8 px3, bhalf8 py3,
    bhalf8 ppv0, bhalf8 ppv1,
    f32x4& acc0, f32x4& acc1, f32x4& acc2, f32x4& acc3) {
  __builtin_amdgcn_s_setprio(1);
  acc0 = __builtin_amdgcn_mfma_f32_16x16x32_bf16(px0, ppv0, acc0, 0, 0, 0);
  acc0 = __builtin_amdgcn_mfma_f32_16x16x32_bf16(py0, ppv1, acc0, 0, 0, 0);
  acc1 = __builtin_amdgcn_mfma_f32_16x16x32_bf16(px1, ppv0, acc1, 0, 0, 0);
  acc1 = __builtin_amdgcn_mfma_f32_16x16x32_bf16(py1, ppv1, acc1, 0, 0, 0);
  acc2 = __builtin_amdgcn_mfma_f32_16x16x32_bf16(px2, ppv0, acc2, 0, 0, 0);
  acc2 = __builtin_amdgcn_mfma_f32_16x16x32_bf16(py2, ppv1, acc2, 0, 0, 0);
  acc3 = __builtin_amdgcn_mfma_f32_16x16x32_bf16(px3, ppv0, acc3, 0, 0, 0);
  acc3 = __builtin_amdgcn_mfma_f32_16x16x32_bf16(py3, ppv1, acc3, 0, 0, 0);
  __builtin_amdgcn_s_setprio(0);
}

// ---------------------------------------------------------------------------
// One 64-key tile step, PIPELINED (T15 form): issue V loads for THIS tile,
// run QK^T MFMAs, then flush the PREVIOUS tile's PV MFMAs (register-only —
// fills the matrix pipe while QK results land), then softmax -> new pending
// P^T packs. The PV for this tile is deferred to the next step (or the final
// flush). Accumulation order across tiles is unchanged -> bit-identical.
// ---------------------------------------------------------------------------
template <bool MASKED>
__device__ __forceinline__ void tile_step(
    const u16* __restrict__ Kb, const char* __restrict__ vf_lane,
    int t0, int grp, int col, int bnd,
    bhalf8 qa0, bhalf8 qa1, bool flushPrev,
    bhalf8& px0, bhalf8& py0, bhalf8& px1, bhalf8& py1,
    bhalf8& px2, bhalf8& py2, bhalf8& px3, bhalf8& py3,
    bhalf8& ppv0, bhalf8& ppv1,
    f32x4& acc0, f32x4& acc1, f32x4& acc2, f32x4& acc3,
    float& lsum) {
  const int swz = col & 7;

  // ---- V^T fragment loads for THIS tile (coalesced; used next step) ----
  const char* vf = vf_lane + (size_t)(t0 >> 6) * 8192;
  bhalf8 nx0 = ldfrag((const u16*)(vf + 0 * 1024));
  bhalf8 ny0 = ldfrag((const u16*)(vf + 1 * 1024));
  bhalf8 nx1 = ldfrag((const u16*)(vf + 2 * 1024));
  bhalf8 ny1 = ldfrag((const u16*)(vf + 3 * 1024));
  bhalf8 nx2 = ldfrag((const u16*)(vf + 4 * 1024));
  bhalf8 ny2 = ldfrag((const u16*)(vf + 5 * 1024));
  bhalf8 nx3 = ldfrag((const u16*)(vf + 6 * 1024));
  bhalf8 ny3 = ldfrag((const u16*)(vf + 7 * 1024));

  f32x4 z = {0.f, 0.f, 0.f, 0.f};
  f32x4 s0 = z, s1 = z, s2 = z, s3 = z;
  {
    const u16* kr0 = Kb + (0 * 16 + col) * 64;
    const u16* kr1 = Kb + (1 * 16 + col) * 64;
    const u16* kr2 = Kb + (2 * 16 + col) * 64;
    const u16* kr3 = Kb + (3 * 16 + col) * 64;
    __builtin_amdgcn_s_setprio(1);
    bhalf8 a0 = ldfrag(kr0 + ((grp ^ swz) * 8));
    s0 = __builtin_amdgcn_mfma_f32_16x16x32_bf16(a0, qa0, s0, 0, 0, 0);
    bhalf8 b0 = ldfrag(kr0 + (((4 + grp) ^ swz) * 8));
    s0 = __builtin_amdgcn_mfma_f32_16x16x32_bf16(b0, qa1, s0, 0, 0, 0);
    bhalf8 a1 = ldfrag(kr1 + ((grp ^ swz) * 8));
    s1 = __builtin_amdgcn_mfma_f32_16x16x32_bf16(a1, qa0, s1, 0, 0, 0);
    bhalf8 b1 = ldfrag(kr1 + (((4 + grp) ^ swz) * 8));
    s1 = __builtin_amdgcn_mfma_f32_16x16x32_bf16(b1, qa1, s1, 0, 0, 0);
    bhalf8 a2 = ldfrag(kr2 + ((grp ^ swz) * 8));
    s2 = __builtin_amdgcn_mfma_f32_16x16x32_bf16(a2, qa0, s2, 0, 0, 0);
    bhalf8 b2 = ldfrag(kr2 + (((4 + grp) ^ swz) * 8));
    s2 = __builtin_amdgcn_mfma_f32_16x16x32_bf16(b2, qa1, s2, 0, 0, 0);
    bhalf8 a3 = ldfrag(kr3 + ((grp ^ swz) * 8));
    s3 = __builtin_amdgcn_mfma_f32_16x16x32_bf16(a3, qa0, s3, 0, 0, 0);
    bhalf8 b3 = ldfrag(kr3 + (((4 + grp) ^ swz) * 8));
    s3 = __builtin_amdgcn_mfma_f32_16x16x32_bf16(b3, qa1, s3, 0, 0, 0);
    __builtin_amdgcn_s_setprio(0);
  }

  // ---- flush PREVIOUS tile's PV while this tile's QK results land ----
  if (flushPrev)
    pv_flush(px0, py0, px1, py1, px2, py2, px3, py3, ppv0, ppv1,
             acc0, acc1, acc2, acc3);

  // softmax (fixed-max exp2(s-16), exact) + pack P^T into pending B-frags
  uint2 w0, w1, w2, w3;
#define SM_C(SC, CB, W)                                                        \
  {                                                                            \
    float p0, p1, p2v, p3;                                                     \
    const int kb = t0 + (CB) + grp * 4;                                        \
    if (MASKED) {                                                              \
      p0  = (kb + 0 <= bnd) ? EXP2(SC[0] - 16.f) : 0.f;                        \
      p1  = (kb + 1 <= bnd) ? EXP2(SC[1] - 16.f) : 0.f;                        \
      p2v = (kb + 2 <= bnd) ? EXP2(SC[2] - 16.f) : 0.f;                        \
      p3  = (kb + 3 <= bnd) ? EXP2(SC[3] - 16.f) : 0.f;                        \
    } else {                                                                   \
      p0  = EXP2(SC[0] - 16.f);                                                \
      p1  = EXP2(SC[1] - 16.f);                                                \
      p2v = EXP2(SC[2] - 16.f);                                                \
      p3  = EXP2(SC[3] - 16.f);                                                \
    }                                                                          \
    lsum += (p0 + p1) + (p2v + p3);                                            \
    W.x = cvt_pk_bf16(p0, p1);                                                 \
    W.y = cvt_pk_bf16(p2v, p3);                                                \
  }
  SM_C(s0, 0,  w0)
  SM_C(s1, 16, w1)
  SM_C(s2, 32, w2)
  SM_C(s3, 48, w3)
#undef SM_C

  {
    Frag16 f0, f1;
    f0.d[0] = w0; f0.d[1] = w1;   // keys blocks 0,1 (k-slots 0..31, kappa-matched)
    f1.d[0] = w2; f1.d[1] = w3;   // keys blocks 2,3 (k-slots 32..63)
    ppv0 = f0.v; ppv1 = f1.v;
  }
  px0 = nx0; py0 = ny0; px1 = nx1; py1 = ny1;
  px2 = nx2; py2 = ny2; px3 = nx3; py3 = ny3;
}

// ---------------------------------------------------------------------------
// Flash attention. Block = 256 thr (4 waves), Q-tile 64 (16 q/wave), K-tile
// 64. Grid = 1024, column-balanced rank->qt map. LDS = 16 KiB (K dbuf only).
// Cross-tile PV pipeline; 1 barrier/tile.
// ---------------------------------------------------------------------------
__global__ __launch_bounds__(256, 4) void attn_mfma_kernel(
    const float* __restrict__ qsrc, const u16* __restrict__ kbf,
    const u16* __restrict__ vfrag, const int* __restrict__ idx,
    float* __restrict__ out) {
  __shared__ u16 KbufA[64 * 64];
  __shared__ u16 KbufB[64 * 64];

  const int blk = (int)blockIdx.x;   // 1024 = 32 qt-ranks x 32 bh (bh fastest)
  const int bh  = blk & 31;
  const int rank = blk >> 5;         // 0..31
  const int rmod = rank & 7;
  const int rdiv = rank >> 3;        // 0..3
  // column-balanced map: {31-rmod, rmod, 23-rmod, 8+rmod}
  const int qt = (rdiv == 0) ? (31 - rmod)
               : (rdiv == 1) ? rmod
               : (rdiv == 2) ? (23 - rmod)
               : (8 + rmod);
  const int q0  = qt * 64;
  const int b   = bh >> 4;
  const int tid  = threadIdx.x;
  const int w    = tid >> 6;
  const int lane = tid & 63;
  const int grp  = lane >> 4;
  const int col  = lane & 15;

  const char* kb_bh = (const char*)(kbf + (size_t)bh * SS * DD);
  const char* vf_lane = (const char*)vfrag + (size_t)bh * (SS * DD * 2) + (size_t)lane * 16;

  const int srow = lane >> 3;
  const int schk = lane & 7;

  const int* idxb = idx + b * QQ + q0;
  const int bnd = idxb[w * 16 + col];      // lane's q-row bound = its RoPE pos
  const int wave_minb = idxb[w * 16];      // idx ascending -> wave min bound
  const int wave_maxb = idxb[w * 16 + 15]; // wave max bound
  const int maxbound  = idxb[63];
  const int ntiles = (maxbound >> 6) + 1;

  // ---- inline q RoPE -> fragments (verified text; pos = bnd) ----
  bhalf8 qa0, qa1;
  {
    const int qrow = q0 + w * 16 + col;
    const float* qr = qsrc + (size_t)(bh * QQ + qrow) * DD;
    const int lof = (grp & 1) * 8;
    float4 A0 = *(const float4*)(qr + lof);
    float4 A1 = *(const float4*)(qr + lof + 4);
    float4 B0 = *(const float4*)(qr + 16 + lof);
    float4 B1 = *(const float4*)(qr + 16 + lof + 4);
    float4 C0 = *(const float4*)(qr + 32 + grp * 8);
    float4 C1 = *(const float4*)(qr + 32 + grp * 8 + 4);
    float xlo[8] = {A0.x, A0.y, A0.z, A0.w, A1.x, A1.y, A1.z, A1.w};
    float xhi[8] = {B0.x, B0.y, B0.z, B0.w, B1.x, B1.y, B1.z, B1.w};
    float xq1[8] = {C0.x, C0.y, C0.z, C0.w, C1.x, C1.y, C1.z, C1.w};
    const float scq = 0.125f * 1.44269504088896f;  // 1/sqrt(64) * log2(e)
    const float fp = (float)bnd;
    Frag16 f0, f1;
#pragma unroll
    for (int j = 0; j < 8; ++j) {
      float ang = fp * exp2f(-0.8304820237218405f * (float)(lof + j));
      float sv, cv;
      __sincosf(ang, &sv, &cv);
      float val = (grp >= 2) ? (xhi[j] * cv + xlo[j] * sv)
                             : (xlo[j] * cv - xhi[j] * sv);
      f0.s[j] = f2bf(val * scq);
      f1.s[j] = f2bf(xq1[j] * scq);
    }
    qa0 = f0.v; qa1 = f1.v;
  }

  f32x4 z = {0.f, 0.f, 0.f, 0.f};
  f32x4 acc0 = z, acc1 = z, acc2 = z, acc3 = z;
  float lsum = 0.f;

  bhalf8 zz = {0, 0, 0, 0, 0, 0, 0, 0};
  bhalf8 px0 = zz, py0 = zz, px1 = zz, py1 = zz;
  bhalf8 px2 = zz, py2 = zz, px3 = zz, py3 = zz;
  bhalf8 ppv0 = zz, ppv1 = zz;
  bool pend = false;

#define TILE_STEP(M, KB, T0)                                                   \
  tile_step<M>(KB, vf_lane, T0, grp, col, bnd, qa0, qa1, pend,                 \
               px0, py0, px1, py1, px2, py2, px3, py3, ppv0, ppv1,             \
               acc0, acc1, acc2, acc3, lsum)

  stage_k(kb_bh, KbufA, 0, w, srow, schk);
  __syncthreads();

  for (int ti = 0; ti < ntiles; ti += 2) {
    const bool has1 = (ti + 1) < ntiles;
    if (has1) stage_k(kb_bh, KbufB, (ti + 1) << 6, w, srow, schk);
    {
      const int t0 = ti << 6;
      if (t0 <= wave_maxb) {   // wave-uniform; later tiles all skipped too
        if (t0 + 63 <= wave_minb) TILE_STEP(false, KbufA, t0);
        else                      TILE_STEP(true,  KbufA, t0);
        pend = true;
      }
    }
    __syncthreads();
    if (has1) {
      if (ti + 2 < ntiles)
        stage_k(kb_bh, KbufA, (ti + 2) << 6, w, srow, schk);
      {
        const int t0 = (ti + 1) << 6;
        if (t0 <= wave_maxb) {
          if (t0 + 63 <= wave_minb) TILE_STEP(false, KbufB, t0);
          else                      TILE_STEP(true,  KbufB, t0);
          pend = true;
        }
      }
      __syncthreads();
    }
  }
#undef TILE_STEP

  // ---- final PV flush for the last computed tile ----
  if (pend)
    pv_flush(px0, py0, px1, py1, px2, py2, px3, py3, ppv0, ppv1,
             acc0, acc1, acc2, acc3);

  // ---- epilogue: reduce l over grp (2 shuffles), coalesced float4 stores ----
  lsum += __shfl_xor(lsum, 16);
  lsum += __shfl_xor(lsum, 32);
  const float inv = 1.f / lsum;
  float* ob = out + (size_t)(bh * QQ + q0 + w * 16 + col) * DD + grp * 4;
  {
    float4 t;
    t.x = acc0[0] * inv; t.y = acc0[1] * inv; t.z = acc0[2] * inv; t.w = acc0[3] * inv;
    *(float4*)(ob + 0) = t;
    t.x = acc1[0] * inv; t.y = acc1[1] * inv; t.z = acc1[2] * inv; t.w = acc1[3] * inv;
    *(float4*)(ob + 16) = t;
    t.x = acc2[0] * inv; t.y = acc2[1] * inv; t.z = acc2[2] * inv; t.w = acc2[3] * inv;
    *(float4*)(ob + 32) = t;
    t.x = acc3[0] * inv; t.y = acc3[1] * inv; t.z = acc3[2] * inv; t.w = acc3[3] * inv;
    *(float4*)(ob + 48) = t;
  }
}

// ---------------------------------------------------------------------------
// Fallback scalar path (round-1, known-good ~2.9ms) if ws too small.
// ---------------------------------------------------------------------------
__global__ __launch_bounds__(64) void attn_fb_kernel(const float* __restrict__ q,
                                                     const float* __restrict__ ksrc,
                                                     const float* __restrict__ v,
                                                     const int* __restrict__ idx,
                                                     float* __restrict__ out) {
  int t = (int)(gridDim.x - 1u - blockIdx.x);
  int sub = t >> 5;
  int bh = t & 31;
  int b = bh >> 4;
  int lane = threadIdx.x;
  int qi = sub * 64 + lane;
  const int bound = idx[b * QQ + qi];

  float qreg[64];
  {
    const float4* qp = (const float4*)(q + ((size_t)bh * QQ + qi) * DD);
#pragma unroll
    for (int i = 0; i < 16; ++i) {
      float4 t4 = qp[i];
      qreg[4 * i] = t4.x; qreg[4 * i + 1] = t4.y;
      qreg[4 * i + 2] = t4.z; qreg[4 * i + 3] = t4.w;
    }
  }
  rope32(qreg, bound);
#pragma unroll
  for (int i = 0; i < 64; ++i) qreg[i] *= 0.125f;

  const float* kbase = ksrc + (size_t)bh * SS * DD;
  const float* vbase = v + (size_t)bh * SS * DD;
  float acc[64];
#pragma unroll
  for (int i = 0; i < 64; ++i) acc[i] = 0.f;
  float mrun = -INFINITY, lrun = 0.f;

  for (int j = 0; j <= bound; ++j) {
    float ka[64];
    const float4* kp = (const float4*)(kbase + (size_t)j * DD);
#pragma unroll
    for (int i = 0; i < 16; ++i) {
      float4 t4 = kp[i];
      ka[4 * i] = t4.x; ka[4 * i + 1] = t4.y;
      ka[4 * i + 2] = t4.z; ka[4 * i + 3] = t4.w;
    }
    rope32(ka, j);
    float s0 = 0.f, s1 = 0.f, s2 = 0.f, s3 = 0.f;
#pragma unroll
    for (int i = 0; i < 16; ++i) {
      s0 = fmaf(qreg[4 * i], ka[4 * i], s0);
      s1 = fmaf(qreg[4 * i + 1], ka[4 * i + 1], s1);
      s2 = fmaf(qreg[4 * i + 2], ka[4 * i + 2], s2);
      s3 = fmaf(qreg[4 * i + 3], ka[4 * i + 3], s3);
    }
    float sc = (s0 + s1) + (s2 + s3);
    if (sc > mrun) {
      float alpha = __expf(mrun - sc);
      lrun *= alpha;
#pragma unroll
      for (int i = 0; i < 64; ++i) acc[i] *= alpha;
      mrun = sc;
    }
    float pw = __expf(sc - mrun);
    lrun += pw;
    const float4* vp = (const float4*)(vbase + (size_t)j * DD);
#pragma unroll
    for (int i = 0; i < 16; ++i) {
      float4 t4 = vp[i];
      acc[4 * i] = fmaf(pw, t4.x, acc[4 * i]);
      acc[4 * i + 1] = fmaf(pw, t4.y, acc[4 * i + 1]);
      acc[4 * i + 2] = fmaf(pw, t4.z, acc[4 * i + 2]);
      acc[4 * i + 3] = fmaf(pw, t4.w, acc[4 * i + 3]);
    }
  }
  float inv = 1.0f / lrun;
  float4* op = (float4*)(out + ((size_t)bh * QQ + qi) * DD);
#pragma unroll
  for (int i = 0; i < 16; ++i) {
    float4 t4;
    t4.x = acc[4 * i] * inv; t4.y = acc[4 * i + 1] * inv;
    t4.z = acc[4 * i + 2] * inv; t4.w = acc[4 * i + 3] * inv;
    op[i] = t4;
  }
}

extern "C" void kernel_launch(void* const* d_in, const int* in_sizes, int n_in,
                              void* d_out, int out_size, void* d_ws, size_t ws_size,
                              hipStream_t stream) {
  (void)in_sizes; (void)n_in; (void)out_size;
  const float* q = (const float*)d_in[0];
  const float* k = (const float*)d_in[1];
  const float* v = (const float*)d_in[2];
  const unsigned char* skip = (const unsigned char*)d_in[5];
  float* out = (float*)d_out;

  char* base = (char*)d_ws;
  int* idx = (int*)base;
  const size_t kbytes = (size_t)BB * HH * SS * DD * 2;
  u16* kbf = (u16*)(base + 16384);
  u16* vfb = (u16*)(base + 16384 + kbytes);
  const size_t need = 16384 + 2 * kbytes;

  if (ws_size >= need) {
    prep_fused_kernel<<<512 + BB * HH * 64 + BB, 256, 0, stream>>>(k, v, skip,
                                                                   kbf, vfb, idx);
    attn_mfma_kernel<<<NQT * 32, 256, 0, stream>>>(q, kbf, vfb, idx, out);
  } else {
    prep_idx_kernel<<<2, 256, 0, stream>>>(skip, idx);
    attn_fb_kernel<<<1024, 64, 0, stream>>>(q, k, v, idx, out);
  }
}

// Round 13
// 283.498 us; speedup vs baseline: 1.1327x; 1.1327x over previous
//
#include <hip/hip_runtime.h>
#include <math.h>

#define BB 2
#define HH 16
#define QQ 2048
#define SS 4096
#define DD 64
#define NRH 16    // half of N_ROTATE=32
#define NQT 32    // q-tiles of 64 per bh

typedef unsigned short u16;
typedef unsigned int   u32;
typedef short bhalf8 __attribute__((ext_vector_type(8)));  // 8 bf16 bit patterns
typedef float f32x4  __attribute__((ext_vector_type(4)));

typedef __attribute__((address_space(1))) const u32 gu32;
typedef __attribute__((address_space(3))) u32 lu32;

#if __has_builtin(__builtin_amdgcn_exp2f)
#define EXP2(x) __builtin_amdgcn_exp2f(x)
#else
#define EXP2(x) exp2f(x)
#endif

union Frag16 { uint4 u; bhalf8 v; u16 s[8]; uint2 d[2]; };

__device__ __forceinline__ u16 f2bf(float f) {  // RNE f32->bf16
  union { float f; u32 u; } c; c.f = f;
  return (u16)((c.u + 0x7FFFu + ((c.u >> 16) & 1u)) >> 16);
}

// packed RNE f32x2 -> bf16x2 (lo = first src)
__device__ __forceinline__ u32 cvt_pk_bf16(float lo, float hi) {
  u32 r;
  asm("v_cvt_pk_bf16_f32 %0, %1, %2" : "=v"(r) : "v"(lo), "v"(hi));
  return r;
}

__device__ __forceinline__ bhalf8 ldfrag(const u16* p) {
  Frag16 f; f.u = *reinterpret_cast<const uint4*>(p); return f.v;
}

__device__ __forceinline__ void rope32(float* x, int pos) {
  const float step = 0.8304820237218405f;  // log2(10000)/16
  const float fp = (float)pos;
#pragma unroll
  for (int i = 0; i < NRH; ++i) {
    float ang = fp * exp2f(-step * (float)i);
    float sv, cv;
    __sincosf(ang, &sv, &cv);
    float a = x[i], b = x[i + NRH];
    x[i]       = a * cv - b * sv;
    x[i + NRH] = b * cv + a * sv;
  }
}

// ---------------------------------------------------------------------------
// idx[b][0..2047] = ascending indices of true entries of skip_mask[b].
// Kept as standalone kernel for the fallback path; main path uses the fused
// prep kernel below.
// ---------------------------------------------------------------------------
__device__ __forceinline__ void prep_idx_body(const unsigned char* __restrict__ sm,
                                              int* __restrict__ idx, int b,
                                              int* wsum, int* modes) {
  const int tid = threadIdx.x;  // 256

  int c = 0;
  for (int i = 0; i < 32; ++i) c += (sm[tid * 32 + i] != 0) ? 1 : 0;
#pragma unroll
  for (int off = 32; off; off >>= 1) c += __shfl_down(c, off);
  if ((tid & 63) == 0) wsum[tid >> 6] = c;
  __syncthreads();
  if (tid == 0) *modes = (wsum[0] + wsum[1] + wsum[2] + wsum[3] > 3000) ? 1 : 0;
  __syncthreads();
  const bool byteMode = (*modes != 0);
  const u32* sm32 = (const u32*)sm;

  const int base = b * SS + tid * 16;
  u32 flags = 0;
  for (int i = 0; i < 16; ++i) {
    bool f = byteMode ? (sm[base + i] != 0) : (sm32[base + i] != 0);
    flags |= ((u32)(f ? 1 : 0)) << i;
  }
  int cnt = __popc(flags);
  int vv = cnt;
#pragma unroll
  for (int off = 1; off < 64; off <<= 1) {
    int t = __shfl_up(vv, off);
    if ((tid & 63) >= off) vv += t;
  }
  __syncthreads();
  if ((tid & 63) == 63) wsum[tid >> 6] = vv;
  __syncthreads();
  int add = 0;
  for (int w2 = 0; w2 < (tid >> 6); ++w2) add += wsum[w2];
  int p = vv - cnt + add;
  for (int i = 0; i < 16; ++i) {
    if (flags & (1u << i)) {
      if (p < QQ) idx[b * QQ + p] = tid * 16 + i;
      ++p;
    }
  }
}

__global__ void prep_idx_kernel(const unsigned char* __restrict__ sm,
                                int* __restrict__ idx) {
  __shared__ int wsum[4];
  __shared__ int modes;
  prep_idx_body(sm, idx, (int)blockIdx.x, wsum, &modes);
}

// ---------------------------------------------------------------------------
// FUSED prep (saves one dispatch vs separate prep_idx):
//   blocks [0,512):      k -> RoPE(pos=j) -> bf16 kbf[bh][j][d]
//   blocks [512,2560):   v -> bf16 transposed vt[bh][d][p] with key
//                        permutation kappa(p) = (p&32)|((p&4)<<2)|((p>>1)&12)|(p&3)
//                        within each 64-key tile (matches swapped-QK^T
//                        in-register P^T fragments).
//   blocks [2560,2562):  skip_mask -> idx (batch = blockIdx - 2560)
// ---------------------------------------------------------------------------
__global__ __launch_bounds__(256) void prep_fused_kernel(
    const float* __restrict__ k, const float* __restrict__ v,
    const unsigned char* __restrict__ skip,
    u16* __restrict__ kbf, u16* __restrict__ vt, int* __restrict__ idx) {
  __shared__ u16 tile[64][72];
  __shared__ int wsum[4];
  __shared__ int modes;
  if (blockIdx.x >= 2560) {
    prep_idx_body(skip, idx, (int)blockIdx.x - 2560, wsum, &modes);
  } else if (blockIdx.x < 512) {
    int r = blockIdx.x * 256 + threadIdx.x;  // 0..131071
    int pos = r & (SS - 1);
    float x[64];
    const float4* src = (const float4*)(k + (size_t)r * DD);
#pragma unroll
    for (int i = 0; i < 16; ++i) {
      float4 t = src[i];
      x[4 * i] = t.x; x[4 * i + 1] = t.y; x[4 * i + 2] = t.z; x[4 * i + 3] = t.w;
    }
    rope32(x, pos);
    u16 tmp[64];
#pragma unroll
    for (int i = 0; i < 64; ++i) tmp[i] = f2bf(x[i]);
    uint4* dst = (uint4*)(kbf + (size_t)r * DD);
#pragma unroll
    for (int i = 0; i < 8; ++i) dst[i] = ((uint4*)tmp)[i];
  } else {
    int blk = (int)blockIdx.x - 512;
    int bh = blk >> 6;
    int jt = blk & 63;
    int t = threadIdx.x;
    int jl = t >> 2;
    int dc = (t & 3) * 16;
    const float4* src = (const float4*)(v + ((size_t)(bh * SS + jt * 64 + jl)) * DD + dc);
#pragma unroll
    for (int i = 0; i < 4; ++i) {
      float4 f = src[i];
      tile[jl][dc + 4 * i]     = f2bf(f.x);
      tile[jl][dc + 4 * i + 1] = f2bf(f.y);
      tile[jl][dc + 4 * i + 2] = f2bf(f.z);
      tile[jl][dc + 4 * i + 3] = f2bf(f.w);
    }
    __syncthreads();
    int d = t >> 2;
    int c = t & 3;            // output positions c*16 .. c*16+15
    u16 o[16];
#pragma unroll
    for (int m = 0; m < 16; ++m) {  // position p holds key kappa(p)
      int p = c * 16 + m;
      int kp = (p & 32) | ((p & 4) << 2) | ((p >> 1) & 12) | (p & 3);
      o[m] = tile[kp][d];
    }
    uint4* dst = (uint4*)(vt + ((size_t)(bh * DD + d)) * SS + jt * 64 + c * 16);
    dst[0] = ((uint4*)o)[0];
    dst[1] = ((uint4*)o)[1];
  }
}

// ---------------------------------------------------------------------------
// Staging: one 64-key K tile + matching V^T tile into LDS via global_load_lds
// (16B/lane), XOR swizzle applied on the GLOBAL address side (LDS slot is the
// wave-forced contiguous one): LDS[row][c] holds global chunk c^(row&7).
// ---------------------------------------------------------------------------
__device__ __forceinline__ void stage_tiles(const char* kb_bh, const char* vt_bh,
                                            u16* Kb, u16* Vb, int t0,
                                            int w, int srow, int schk) {
#pragma unroll
  for (int p2 = 0; p2 < 2; ++p2) {
    const int rr = w * 16 + p2 * 8 + srow;
    {
      const char* g = kb_bh + (size_t)(t0 + rr) * 128 + ((schk ^ (rr & 7)) * 16);
      lu32* l = (lu32*)((char*)Kb + (w * 16 + p2 * 8) * 128);
      __builtin_amdgcn_global_load_lds((gu32*)g, l, 16, 0, 0);
    }
    {
      const char* g = vt_bh + (size_t)rr * (SS * 2) + t0 * 2 + ((schk ^ (rr & 7)) * 16);
      lu32* l = (lu32*)((char*)Vb + (w * 16 + p2 * 8) * 128);
      __builtin_amdgcn_global_load_lds((gu32*)g, l, 16, 0, 0);
    }
  }
}

// ---------------------------------------------------------------------------
// One 64-key tile, one wave, 16 q rows — SWAPPED-OPERAND form (round-6,
// verified). QK^T = mfma(A=K-frag, B=Q-frag); lane holds
// S^T[key=c*16+grp*4+r][q=col]. Softmax per-lane vs the lane's single bound,
// cvt_pk packs P^T straight into the PV B-fragment — P never touches LDS.
// PV = mfma(A=V^T-frag, B=P^T) accumulating O^T[d=grp*4+r+16c][q=col].
// ---------------------------------------------------------------------------
template <bool MASKED>
__device__ __forceinline__ void attn_tile(
    const u16* __restrict__ Kb, const u16* __restrict__ Vb,
    int t0, int grp, int col, int bnd,
    bhalf8 qa0, bhalf8 qa1,
    f32x4& acc0, f32x4& acc1, f32x4& acc2, f32x4& acc3,
    float& lsum) {
  const int swz = col & 7;
  f32x4 z = {0.f, 0.f, 0.f, 0.f};
  f32x4 s0 = z, s1 = z, s2 = z, s3 = z;
  {
    const u16* kr0 = Kb + (0 * 16 + col) * 64;
    const u16* kr1 = Kb + (1 * 16 + col) * 64;
    const u16* kr2 = Kb + (2 * 16 + col) * 64;
    const u16* kr3 = Kb + (3 * 16 + col) * 64;
    __builtin_amdgcn_s_setprio(1);
    bhalf8 a0 = ldfrag(kr0 + ((grp ^ swz) * 8));
    s0 = __builtin_amdgcn_mfma_f32_16x16x32_bf16(a0, qa0, s0, 0, 0, 0);
    bhalf8 b0 = ldfrag(kr0 + (((4 + grp) ^ swz) * 8));
    s0 = __builtin_amdgcn_mfma_f32_16x16x32_bf16(b0, qa1, s0, 0, 0, 0);
    bhalf8 a1 = ldfrag(kr1 + ((grp ^ swz) * 8));
    s1 = __builtin_amdgcn_mfma_f32_16x16x32_bf16(a1, qa0, s1, 0, 0, 0);
    bhalf8 b1 = ldfrag(kr1 + (((4 + grp) ^ swz) * 8));
    s1 = __builtin_amdgcn_mfma_f32_16x16x32_bf16(b1, qa1, s1, 0, 0, 0);
    bhalf8 a2 = ldfrag(kr2 + ((grp ^ swz) * 8));
    s2 = __builtin_amdgcn_mfma_f32_16x16x32_bf16(a2, qa0, s2, 0, 0, 0);
    bhalf8 b2 = ldfrag(kr2 + (((4 + grp) ^ swz) * 8));
    s2 = __builtin_amdgcn_mfma_f32_16x16x32_bf16(b2, qa1, s2, 0, 0, 0);
    bhalf8 a3 = ldfrag(kr3 + ((grp ^ swz) * 8));
    s3 = __builtin_amdgcn_mfma_f32_16x16x32_bf16(a3, qa0, s3, 0, 0, 0);
    bhalf8 b3 = ldfrag(kr3 + (((4 + grp) ^ swz) * 8));
    s3 = __builtin_amdgcn_mfma_f32_16x16x32_bf16(b3, qa1, s3, 0, 0, 0);
    __builtin_amdgcn_s_setprio(0);
  }

  // softmax (fixed-max exp2(s-16), exact) + pack P^T into PV B-frags in-lane
  uint2 w0, w1, w2, w3;
#define SM_C(SC, CB, W)                                                        \
  {                                                                            \
    float p0, p1, p2v, p3;                                                     \
    const int kb = t0 + (CB) + grp * 4;                                        \
    if (MASKED) {                                                              \
      p0  = (kb + 0 <= bnd) ? EXP2(SC[0] - 16.f) : 0.f;                        \
      p1  = (kb + 1 <= bnd) ? EXP2(SC[1] - 16.f) : 0.f;                        \
      p2v = (kb + 2 <= bnd) ? EXP2(SC[2] - 16.f) : 0.f;                        \
      p3  = (kb + 3 <= bnd) ? EXP2(SC[3] - 16.f) : 0.f;                        \
    } else {                                                                   \
      p0  = EXP2(SC[0] - 16.f);                                                \
      p1  = EXP2(SC[1] - 16.f);                                                \
      p2v = EXP2(SC[2] - 16.f);                                                \
      p3  = EXP2(SC[3] - 16.f);                                                \
    }                                                                          \
    lsum += (p0 + p1) + (p2v + p3);                                            \
    W.x = cvt_pk_bf16(p0, p1);                                                 \
    W.y = cvt_pk_bf16(p2v, p3);                                                \
  }
  SM_C(s0, 0,  w0)
  SM_C(s1, 16, w1)
  SM_C(s2, 32, w2)
  SM_C(s3, 48, w3)
#undef SM_C

  bhalf8 pv0, pv1;
  {
    Frag16 f0, f1;
    f0.d[0] = w0; f0.d[1] = w1;   // keys blocks 0,1  (k-slots 0..31, kappa-matched)
    f1.d[0] = w2; f1.d[1] = w3;   // keys blocks 2,3  (k-slots 32..63)
    pv0 = f0.v; pv1 = f1.v;
  }

  {
    const u16* vr0 = Vb + (0  + col) * 64;
    const u16* vr1 = Vb + (16 + col) * 64;
    const u16* vr2 = Vb + (32 + col) * 64;
    const u16* vr3 = Vb + (48 + col) * 64;
    __builtin_amdgcn_s_setprio(1);
    bhalf8 x0 = ldfrag(vr0 + ((grp ^ swz) * 8));
    acc0 = __builtin_amdgcn_mfma_f32_16x16x32_bf16(x0, pv0, acc0, 0, 0, 0);
    bhalf8 y0 = ldfrag(vr0 + (((4 + grp) ^ swz) * 8));
    acc0 = __builtin_amdgcn_mfma_f32_16x16x32_bf16(y0, pv1, acc0, 0, 0, 0);
    bhalf8 x1 = ldfrag(vr1 + ((grp ^ swz) * 8));
    acc1 = __builtin_amdgcn_mfma_f32_16x16x32_bf16(x1, pv0, acc1, 0, 0, 0);
    bhalf8 y1 = ldfrag(vr1 + (((4 + grp) ^ swz) * 8));
    acc1 = __builtin_amdgcn_mfma_f32_16x16x32_bf16(y1, pv1, acc1, 0, 0, 0);
    bhalf8 x2 = ldfrag(vr2 + ((grp ^ swz) * 8));
    acc2 = __builtin_amdgcn_mfma_f32_16x16x32_bf16(x2, pv0, acc2, 0, 0, 0);
    bhalf8 y2 = ldfrag(vr2 + (((4 + grp) ^ swz) * 8));
    acc2 = __builtin_amdgcn_mfma_f32_16x16x32_bf16(y2, pv1, acc2, 0, 0, 0);
    bhalf8 x3 = ldfrag(vr3 + ((grp ^ swz) * 8));
    acc3 = __builtin_amdgcn_mfma_f32_16x16x32_bf16(x3, pv0, acc3, 0, 0, 0);
    bhalf8 y3 = ldfrag(vr3 + (((4 + grp) ^ swz) * 8));
    acc3 = __builtin_amdgcn_mfma_f32_16x16x32_bf16(y3, pv1, acc3, 0, 0, 0);
    __builtin_amdgcn_s_setprio(0);
  }
}

// ---------------------------------------------------------------------------
// Flash attention (best verified configuration — round-9 bench, 282.8 us).
// Block = 256 thr (4 waves), Q-tile 64 (16 q/wave), K-tile 64. Grid = 1024 —
// all blocks resident (4/CU), column-balanced rank->qt map (each CU column
// {r, r+8, r+16, r+24} sums (qt+1) to 66). LDS = 48 KiB (K/V dbuf, no P
// buffer, no fence — P in registers via swapped-operand QK^T). 1 barrier/tile.
// ---------------------------------------------------------------------------
__global__ __launch_bounds__(256, 4) void attn_mfma_kernel(
    const float* __restrict__ qsrc, const u16* __restrict__ kbf,
    const u16* __restrict__ vt, const int* __restrict__ idx,
    float* __restrict__ out) {
  __shared__ u16 KbufA[64 * 64];
  __shared__ u16 VbufA[64 * 64];
  __shared__ u16 KbufB[64 * 64];
  __shared__ u16 VbufB[64 * 64];

  const int blk = (int)blockIdx.x;   // 1024 = 32 qt-ranks x 32 bh (bh fastest)
  const int bh  = blk & 31;
  const int rank = blk >> 5;         // 0..31
  const int rmod = rank & 7;
  const int rdiv = rank >> 3;        // 0..3
  // column-balanced map: {31-rmod, rmod, 23-rmod, 8+rmod}
  const int qt = (rdiv == 0) ? (31 - rmod)
               : (rdiv == 1) ? rmod
               : (rdiv == 2) ? (23 - rmod)
               : (8 + rmod);
  const int q0  = qt * 64;
  const int b   = bh >> 4;
  const int tid  = threadIdx.x;
  const int w    = tid >> 6;
  const int lane = tid & 63;
  const int grp  = lane >> 4;
  const int col  = lane & 15;

  const char* kb_bh = (const char*)(kbf + (size_t)bh * SS * DD);
  const char* vt_bh = (const char*)(vt + (size_t)bh * DD * SS);

  const int srow = lane >> 3;
  const int schk = lane & 7;

  const int* idxb = idx + b * QQ + q0;
  const int bnd = idxb[w * 16 + col];      // lane's q-row bound = its RoPE pos
  const int wave_minb = idxb[w * 16];      // idx ascending -> wave min bound
  const int wave_maxb = idxb[w * 16 + 15]; // wave max bound
  const int maxbound  = idxb[63];
  const int ntiles = (maxbound >> 6) + 1;

  // ---- inline q RoPE -> fragments (verified text; pos = bnd) ----
  bhalf8 qa0, qa1;
  {
    const int qrow = q0 + w * 16 + col;
    const float* qr = qsrc + (size_t)(bh * QQ + qrow) * DD;
    const int lof = (grp & 1) * 8;
    float4 A0 = *(const float4*)(qr + lof);
    float4 A1 = *(const float4*)(qr + lof + 4);
    float4 B0 = *(const float4*)(qr + 16 + lof);
    float4 B1 = *(const float4*)(qr + 16 + lof + 4);
    float4 C0 = *(const float4*)(qr + 32 + grp * 8);
    float4 C1 = *(const float4*)(qr + 32 + grp * 8 + 4);
    float xlo[8] = {A0.x, A0.y, A0.z, A0.w, A1.x, A1.y, A1.z, A1.w};
    float xhi[8] = {B0.x, B0.y, B0.z, B0.w, B1.x, B1.y, B1.z, B1.w};
    float xq1[8] = {C0.x, C0.y, C0.z, C0.w, C1.x, C1.y, C1.z, C1.w};
    const float scq = 0.125f * 1.44269504088896f;  // 1/sqrt(64) * log2(e)
    const float fp = (float)bnd;
    Frag16 f0, f1;
#pragma unroll
    for (int j = 0; j < 8; ++j) {
      float ang = fp * exp2f(-0.8304820237218405f * (float)(lof + j));
      float sv, cv;
      __sincosf(ang, &sv, &cv);
      float val = (grp >= 2) ? (xhi[j] * cv + xlo[j] * sv)
                             : (xlo[j] * cv - xhi[j] * sv);
      f0.s[j] = f2bf(val * scq);
      f1.s[j] = f2bf(xq1[j] * scq);
    }
    qa0 = f0.v; qa1 = f1.v;
  }

  f32x4 z = {0.f, 0.f, 0.f, 0.f};
  f32x4 acc0 = z, acc1 = z, acc2 = z, acc3 = z;
  float lsum = 0.f;

#define ATTN_CALL(M, KB, VB, T0)                                               \
  attn_tile<M>(KB, VB, T0, grp, col, bnd, qa0, qa1, acc0, acc1, acc2, acc3, lsum)

  stage_tiles(kb_bh, vt_bh, KbufA, VbufA, 0, w, srow, schk);
  __syncthreads();

  for (int ti = 0; ti < ntiles; ti += 2) {
    const bool has1 = (ti + 1) < ntiles;
    if (has1) stage_tiles(kb_bh, vt_bh, KbufB, VbufB, (ti + 1) << 6, w, srow, schk);
    {
      const int t0 = ti << 6;
      if (t0 <= wave_maxb) {   // wave-uniform; skipped tiles contribute zero P
        if (t0 + 63 <= wave_minb) ATTN_CALL(false, KbufA, VbufA, t0);
        else                      ATTN_CALL(true,  KbufA, VbufA, t0);
      }
    }
    __syncthreads();
    if (has1) {
      if (ti + 2 < ntiles)
        stage_tiles(kb_bh, vt_bh, KbufA, VbufA, (ti + 2) << 6, w, srow, schk);
      {
        const int t0 = (ti + 1) << 6;
        if (t0 <= wave_maxb) {
          if (t0 + 63 <= wave_minb) ATTN_CALL(false, KbufB, VbufB, t0);
          else                      ATTN_CALL(true,  KbufB, VbufB, t0);
        }
      }
      __syncthreads();
    }
  }
#undef ATTN_CALL

  // ---- epilogue: reduce l over grp (2 shuffles), coalesced float4 stores ----
  lsum += __shfl_xor(lsum, 16);
  lsum += __shfl_xor(lsum, 32);
  const float inv = 1.f / lsum;
  float* ob = out + (size_t)(bh * QQ + q0 + w * 16 + col) * DD + grp * 4;
  {
    float4 t;
    t.x = acc0[0] * inv; t.y = acc0[1] * inv; t.z = acc0[2] * inv; t.w = acc0[3] * inv;
    *(float4*)(ob + 0) = t;
    t.x = acc1[0] * inv; t.y = acc1[1] * inv; t.z = acc1[2] * inv; t.w = acc1[3] * inv;
    *(float4*)(ob + 16) = t;
    t.x = acc2[0] * inv; t.y = acc2[1] * inv; t.z = acc2[2] * inv; t.w = acc2[3] * inv;
    *(float4*)(ob + 32) = t;
    t.x = acc3[0] * inv; t.y = acc3[1] * inv; t.z = acc3[2] * inv; t.w = acc3[3] * inv;
    *(float4*)(ob + 48) = t;
  }
}

// ---------------------------------------------------------------------------
// Fallback scalar path (round-1, known-good ~2.9ms) if ws too small.
// ---------------------------------------------------------------------------
__global__ __launch_bounds__(64) void attn_fb_kernel(const float* __restrict__ q,
                                                     const float* __restrict__ ksrc,
                                                     const float* __restrict__ v,
                                                     const int* __restrict__ idx,
                                                     float* __restrict__ out) {
  int t = (int)(gridDim.x - 1u - blockIdx.x);
  int sub = t >> 5;
  int bh = t & 31;
  int b = bh >> 4;
  int lane = threadIdx.x;
  int qi = sub * 64 + lane;
  const int bound = idx[b * QQ + qi];

  float qreg[64];
  {
    const float4* qp = (const float4*)(q + ((size_t)bh * QQ + qi) * DD);
#pragma unroll
    for (int i = 0; i < 16; ++i) {
      float4 t4 = qp[i];
      qreg[4 * i] = t4.x; qreg[4 * i + 1] = t4.y;
      qreg[4 * i + 2] = t4.z; qreg[4 * i + 3] = t4.w;
    }
  }
  rope32(qreg, bound);
#pragma unroll
  for (int i = 0; i < 64; ++i) qreg[i] *= 0.125f;

  const float* kbase = ksrc + (size_t)bh * SS * DD;
  const float* vbase = v + (size_t)bh * SS * DD;
  float acc[64];
#pragma unroll
  for (int i = 0; i < 64; ++i) acc[i] = 0.f;
  float mrun = -INFINITY, lrun = 0.f;

  for (int j = 0; j <= bound; ++j) {
    float ka[64];
    const float4* kp = (const float4*)(kbase + (size_t)j * DD);
#pragma unroll
    for (int i = 0; i < 16; ++i) {
      float4 t4 = kp[i];
      ka[4 * i] = t4.x; ka[4 * i + 1] = t4.y;
      ka[4 * i + 2] = t4.z; ka[4 * i + 3] = t4.w;
    }
    rope32(ka, j);
    float s0 = 0.f, s1 = 0.f, s2 = 0.f, s3 = 0.f;
#pragma unroll
    for (int i = 0; i < 16; ++i) {
      s0 = fmaf(qreg[4 * i], ka[4 * i], s0);
      s1 = fmaf(qreg[4 * i + 1], ka[4 * i + 1], s1);
      s2 = fmaf(qreg[4 * i + 2], ka[4 * i + 2], s2);
      s3 = fmaf(qreg[4 * i + 3], ka[4 * i + 3], s3);
    }
    float sc = (s0 + s1) + (s2 + s3);
    if (sc > mrun) {
      float alpha = __expf(mrun - sc);
      lrun *= alpha;
#pragma unroll
      for (int i = 0; i < 64; ++i) acc[i] *= alpha;
      mrun = sc;
    }
    float pw = __expf(sc - mrun);
    lrun += pw;
    const float4* vp = (const float4*)(vbase + (size_t)j * DD);
#pragma unroll
    for (int i = 0; i < 16; ++i) {
      float4 t4 = vp[i];
      acc[4 * i] = fmaf(pw, t4.x, acc[4 * i]);
      acc[4 * i + 1] = fmaf(pw, t4.y, acc[4 * i + 1]);
      acc[4 * i + 2] = fmaf(pw, t4.z, acc[4 * i + 2]);
      acc[4 * i + 3] = fmaf(pw, t4.w, acc[4 * i + 3]);
    }
  }
  float inv = 1.0f / lrun;
  float4* op = (float4*)(out + ((size_t)bh * QQ + qi) * DD);
#pragma unroll
  for (int i = 0; i < 16; ++i) {
    float4 t4;
    t4.x = acc[4 * i] * inv; t4.y = acc[4 * i + 1] * inv;
    t4.z = acc[4 * i + 2] * inv; t4.w = acc[4 * i + 3] * inv;
    op[i] = t4;
  }
}

extern "C" void kernel_launch(void* const* d_in, const int* in_sizes, int n_in,
                              void* d_out, int out_size, void* d_ws, size_t ws_size,
                              hipStream_t stream) {
  (void)in_sizes; (void)n_in; (void)out_size;
  const float* q = (const float*)d_in[0];
  const float* k = (const float*)d_in[1];
  const float* v = (const float*)d_in[2];
  const unsigned char* skip = (const unsigned char*)d_in[5];
  float* out = (float*)d_out;

  char* base = (char*)d_ws;
  int* idx = (int*)base;
  const size_t kbytes = (size_t)BB * HH * SS * DD * 2;
  u16* kbf = (u16*)(base + 16384);
  u16* vtb = (u16*)(base + 16384 + kbytes);
  const size_t need = 16384 + 2 * kbytes;

  if (ws_size >= need) {
    prep_fused_kernel<<<512 + BB * HH * 64 + BB, 256, 0, stream>>>(k, v, skip,
                                                                   kbf, vtb, idx);
    attn_mfma_kernel<<<NQT * 32, 256, 0, stream>>>(q, kbf, vtb, idx, out);
  } else {
    prep_idx_kernel<<<2, 256, 0, stream>>>(skip, idx);
    attn_fb_kernel<<<1024, 64, 0, stream>>>(q, k, v, idx, out);
  }
}